// Round 1
// baseline (1293.171 us; speedup 1.0000x reference)
//
#include <hip/hip_runtime.h>
#include <hip/hip_bf16.h>

// Problem: B=32, C=32, H=W=256, regions 4x4 of 64x64.
// Per (region p, channel c): mean/var over (B, 64, 64) = 131072 elems.
// y = (x-mean)*rsqrt(var+eps)*gamma + beta; prelu; 3x3 conv per region
// (zero padding at region borders), + bias.

#define EPS 1e-5f

// ---------------- Kernel 1: per-(b,c,p) partial sums ----------------
__global__ __launch_bounds__(256) void stats_partial(
    const float* __restrict__ x, float* __restrict__ ws_sum,
    float* __restrict__ ws_sq) {
  int idx = blockIdx.x;            // b*512 + c*16 + p
  int b = idx >> 9;
  int c = (idx >> 4) & 31;
  int p = idx & 15;
  int R = p >> 2, Cc = p & 3;
  const float* base = x + (((size_t)(b * 32 + c) * 256 + R * 64) * 256) + Cc * 64;

  float s = 0.f, q = 0.f;
  int tid = threadIdx.x;
#pragma unroll
  for (int it = 0; it < 4; ++it) {
    int l = tid + it * 256;        // 0..1023 float4s
    int row = l >> 4, c4 = l & 15;
    const float4 v =
        *reinterpret_cast<const float4*>(base + row * 256 + c4 * 4);
    s += (v.x + v.y) + (v.z + v.w);
    q += (v.x * v.x + v.y * v.y) + (v.z * v.z + v.w * v.w);
  }
  // wave64 reduce
#pragma unroll
  for (int off = 32; off; off >>= 1) {
    s += __shfl_down(s, off);
    q += __shfl_down(q, off);
  }
  __shared__ float ls[4], lq[4];
  int wid = tid >> 6, lane = tid & 63;
  if (lane == 0) { ls[wid] = s; lq[wid] = q; }
  __syncthreads();
  if (tid == 0) {
    float S = (ls[0] + ls[1]) + (ls[2] + ls[3]);
    float Q = (lq[0] + lq[1]) + (lq[2] + lq[3]);
    ws_sum[idx] = S;
    ws_sq[idx] = Q;
  }
}

// ---------------- Kernel 2: finalize per-(p,c) scale/shift ----------------
__global__ __launch_bounds__(512) void stats_finalize(
    const float* __restrict__ ws_sum, const float* __restrict__ ws_sq,
    const float* __restrict__ gamma, const float* __restrict__ beta,
    float* __restrict__ wsA, float* __restrict__ wsB) {
  int j = threadIdx.x;             // 0..511
  int p = j >> 5, c = j & 31;
  float S = 0.f, Q = 0.f;
#pragma unroll
  for (int b = 0; b < 32; ++b) {
    int idx = b * 512 + c * 16 + p;
    S += ws_sum[idx];
    Q += ws_sq[idx];
  }
  const float inv = 1.0f / 131072.0f;
  float mean = S * inv;
  float var = Q * inv - mean * mean;
  float rstd = rsqrtf(var + EPS);
  float a = rstd * gamma[c];
  float bb = beta[c] - mean * a;
  wsA[p * 32 + c] = a;
  wsB[p * 32 + c] = bb;
}

// ---------------- Kernel 3: normalize + prelu + 3x3 conv + bias ----------------
// block = (b, p, row-tile rt of 4 rows). 256 threads, 1 output pixel/thread,
// 32 fp32 accumulators (all 32 output channels).
__global__ __launch_bounds__(256) void conv_main(
    const float* __restrict__ x, const float* __restrict__ conv_w,
    const float* __restrict__ conv_b, const float* __restrict__ prelu_a,
    const float* __restrict__ wsA, const float* __restrict__ wsB,
    float* __restrict__ out) {
  __shared__ float lds[32][6][66];   // [ic][row(-1..+4)][col(-1..64)] 50688 B

  int blk = blockIdx.x;              // b*256 + p*16 + rt
  int rt = blk & 15;
  int p = (blk >> 4) & 15;
  int b = blk >> 8;
  int R = p >> 2, Cc = p & 3;
  int h0 = rt * 4;
  int tid = threadIdx.x;
  float pa = prelu_a[0];

  // ---- stage normalized+prelu'd inputs into LDS (6 rows x 64 cols x 32 ch)
#pragma unroll
  for (int it = 0; it < 12; ++it) {
    int l = tid + it * 256;          // 0..3071 float4s
    int ch = l / 96;
    int rem = l - ch * 96;
    int row = rem >> 4, c4 = rem & 15;
    int hh = h0 - 1 + row;           // region-local input row
    float4 v = make_float4(0.f, 0.f, 0.f, 0.f);
    if (hh >= 0 && hh < 64) {
      v = *reinterpret_cast<const float4*>(
          x + (((size_t)(b * 32 + ch) * 256 + R * 64 + hh) * 256) + Cc * 64 +
          c4 * 4);
      float a = wsA[p * 32 + ch];
      float bb = wsB[p * 32 + ch];
      v.x = a * v.x + bb; v.x = v.x > 0.f ? v.x : pa * v.x;
      v.y = a * v.y + bb; v.y = v.y > 0.f ? v.y : pa * v.y;
      v.z = a * v.z + bb; v.z = v.z > 0.f ? v.z : pa * v.z;
      v.w = a * v.w + bb; v.w = v.w > 0.f ? v.w : pa * v.w;
    }
    float* dst = &lds[ch][row][1 + c4 * 4];
    dst[0] = v.x; dst[1] = v.y; dst[2] = v.z; dst[3] = v.w;
  }
  // zero left/right halo columns
  if (tid < 192) {
    int ch = tid / 6, row = tid - (tid / 6) * 6;
    lds[ch][row][0] = 0.f;
    lds[ch][row][65] = 0.f;
  }
  __syncthreads();

  // ---- compute: each thread = 1 pixel, 32 output channels
  int r = tid >> 6;                  // 0..3 within tile
  int cl = tid & 63;                 // 0..63 column

  float acc[32];
#pragma unroll
  for (int oc = 0; oc < 32; ++oc) acc[oc] = conv_b[oc];

  for (int ic = 0; ic < 32; ++ic) {
    float n0 = lds[ic][r + 0][cl + 0];
    float n1 = lds[ic][r + 0][cl + 1];
    float n2 = lds[ic][r + 0][cl + 2];
    float n3 = lds[ic][r + 1][cl + 0];
    float n4 = lds[ic][r + 1][cl + 1];
    float n5 = lds[ic][r + 1][cl + 2];
    float n6 = lds[ic][r + 2][cl + 0];
    float n7 = lds[ic][r + 2][cl + 1];
    float n8 = lds[ic][r + 2][cl + 2];
    const float* wp = conv_w + ic * 9;   // + oc*288 below; uniform -> s_load
#pragma unroll
    for (int oc = 0; oc < 32; ++oc) {
      const float* w = wp + oc * 288;
      float a = acc[oc];
      a = fmaf(w[0], n0, a);
      a = fmaf(w[1], n1, a);
      a = fmaf(w[2], n2, a);
      a = fmaf(w[3], n3, a);
      a = fmaf(w[4], n4, a);
      a = fmaf(w[5], n5, a);
      a = fmaf(w[6], n6, a);
      a = fmaf(w[7], n7, a);
      a = fmaf(w[8], n8, a);
      acc[oc] = a;
    }
  }

  // ---- store: out[b][oc][R*64+h0+r][Cc*64+cl]
  float* obase =
      out + (size_t)b * 32 * 65536 + (size_t)(R * 64 + h0 + r) * 256 + Cc * 64 + cl;
#pragma unroll
  for (int oc = 0; oc < 32; ++oc) obase[(size_t)oc * 65536] = acc[oc];
}

extern "C" void kernel_launch(void* const* d_in, const int* in_sizes, int n_in,
                              void* d_out, int out_size, void* d_ws,
                              size_t ws_size, hipStream_t stream) {
  const float* x = (const float*)d_in[0];
  const float* gamma = (const float*)d_in[1];
  const float* beta = (const float*)d_in[2];
  const float* prelu_a = (const float*)d_in[3];
  const float* conv_w = (const float*)d_in[4];
  const float* conv_b = (const float*)d_in[5];
  float* out = (float*)d_out;

  float* ws = (float*)d_ws;
  float* ws_sum = ws;              // 16384
  float* ws_sq = ws + 16384;       // 16384
  float* wsA = ws + 32768;         // 512
  float* wsB = ws + 33280;         // 512

  stats_partial<<<16384, 256, 0, stream>>>(x, ws_sum, ws_sq);
  stats_finalize<<<1, 512, 0, stream>>>(ws_sum, ws_sq, gamma, beta, wsA, wsB);
  conv_main<<<8192, 256, 0, stream>>>(x, conv_w, conv_b, prelu_a, wsA, wsB,
                                      out);
}

// Round 2
// 206.184 us; speedup vs baseline: 6.2719x; 6.2719x over previous
//
#include <hip/hip_runtime.h>
#include <hip/hip_bf16.h>

// B=32, C=32, H=W=256, regions 4x4 of 64x64.
// Per (region p, channel c): mean/var over (B,64,64). Normalize+PReLU, then
// 3x3 conv per region (zero-padded at region borders) + bias.
// Conv via bf16 MFMA implicit-GEMM: m=oc, n=pixel, k=ic; 9 taps accumulate.

#define EPS 1e-5f

typedef float f32x4 __attribute__((ext_vector_type(4)));
typedef __bf16 bf16x8 __attribute__((ext_vector_type(8)));
typedef short short8 __attribute__((ext_vector_type(8)));

__device__ inline short f2bf(float f) {
  union { __hip_bfloat16 h; short s; } u;
  u.h = __float2bfloat16(f);
  return u.s;
}

// ---------------- Kernel 1: per-(b,c,p) partial sums ----------------
__global__ __launch_bounds__(256) void stats_partial(
    const float* __restrict__ x, float* __restrict__ ws_sum,
    float* __restrict__ ws_sq) {
  int idx = blockIdx.x;            // b*512 + c*16 + p
  int b = idx >> 9;
  int c = (idx >> 4) & 31;
  int p = idx & 15;
  int R = p >> 2, Cc = p & 3;
  const float* base = x + (((size_t)(b * 32 + c) * 256 + R * 64) * 256) + Cc * 64;

  float s = 0.f, q = 0.f;
  int tid = threadIdx.x;
#pragma unroll
  for (int it = 0; it < 4; ++it) {
    int l = tid + it * 256;        // 0..1023 float4s
    int row = l >> 4, c4 = l & 15;
    const float4 v =
        *reinterpret_cast<const float4*>(base + row * 256 + c4 * 4);
    s += (v.x + v.y) + (v.z + v.w);
    q += (v.x * v.x + v.y * v.y) + (v.z * v.z + v.w * v.w);
  }
#pragma unroll
  for (int off = 32; off; off >>= 1) {
    s += __shfl_down(s, off);
    q += __shfl_down(q, off);
  }
  __shared__ float ls[4], lq[4];
  int wid = tid >> 6, lane = tid & 63;
  if (lane == 0) { ls[wid] = s; lq[wid] = q; }
  __syncthreads();
  if (tid == 0) {
    ws_sum[idx] = (ls[0] + ls[1]) + (ls[2] + ls[3]);
    ws_sq[idx] = (lq[0] + lq[1]) + (lq[2] + lq[3]);
  }
}

// ---------------- Kernel 2: finalize per-(p,c) scale/shift ----------------
__global__ __launch_bounds__(512) void stats_finalize(
    const float* __restrict__ ws_sum, const float* __restrict__ ws_sq,
    const float* __restrict__ gamma, const float* __restrict__ beta,
    float* __restrict__ wsA, float* __restrict__ wsB) {
  int j = threadIdx.x;             // 0..511
  int p = j >> 5, c = j & 31;
  float S = 0.f, Q = 0.f;
#pragma unroll
  for (int b = 0; b < 32; ++b) {
    int idx = b * 512 + c * 16 + p;
    S += ws_sum[idx];
    Q += ws_sq[idx];
  }
  const float inv = 1.0f / 131072.0f;
  float mean = S * inv;
  float var = Q * inv - mean * mean;
  float rstd = rsqrtf(var + EPS);
  float a = rstd * gamma[c];
  float bb = beta[c] - mean * a;
  wsA[p * 32 + c] = a;
  wsB[p * 32 + c] = bb;
}

// ---------------- Kernel 3: pack conv_w into MFMA A-fragments ----------------
// wfrag[(t*2+h)*64 + lane] = 8 bf16: A[m=oc][k=ic] for tap t, oc-half h.
// lane: oc = h*16 + (lane&15); ic = (lane>>4)*8 + j.
__global__ __launch_bounds__(256) void weights_prep(
    const float* __restrict__ conv_w, unsigned short* __restrict__ wfrag) {
  int idx = blockIdx.x * 256 + threadIdx.x;
  if (idx >= 18 * 64) return;
  int lane = idx & 63;
  int th = idx >> 6;               // t*2 + h
  int t = th >> 1, h = th & 1;
  int dy = t / 3, dx = t - dy * 3;
  int oc = h * 16 + (lane & 15);
  int ic0 = (lane >> 4) * 8;
#pragma unroll
  for (int j = 0; j < 8; ++j) {
    float w = conv_w[((oc * 32 + ic0 + j) * 3 + dy) * 3 + dx];
    wfrag[(size_t)idx * 8 + j] = (unsigned short)f2bf(w);
  }
}

// ---------------- Kernel 4: normalize+prelu -> LDS bf16 -> MFMA conv ----------------
// block = (b, p, rt): 8 output rows x 64 cols of one region. 4 waves.
// LDS: [10 rows][66 cols][32 ic] bf16 (col 0 and 65 = zero halo).
__global__ __launch_bounds__(256) void conv_mfma(
    const float* __restrict__ x, const unsigned short* __restrict__ wfrag,
    const float* __restrict__ conv_b, const float* __restrict__ prelu_a,
    const float* __restrict__ wsA, const float* __restrict__ wsB,
    float* __restrict__ out) {
  __shared__ short lds_y[10 * 66 * 32];  // 42240 B

  int blk = blockIdx.x;              // b*128 + p*8 + rt
  int rt = blk & 7;
  int p = (blk >> 3) & 15;
  int b = blk >> 7;
  int R = p >> 2, Cc = p & 3;
  int h0 = rt * 8;
  int tid = threadIdx.x;
  int lane = tid & 63;
  float pa = prelu_a[0];

  // zero the left/right halo columns (10 rows x 2 cols x 4 ic-slices)
  if (tid < 80) {
    int sr = tid >> 3;
    int rem = tid & 7;
    int colh = (rem & 1) ? 65 : 0;
    int s = rem >> 1;
    short8 z = {0, 0, 0, 0, 0, 0, 0, 0};
    *reinterpret_cast<short8*>(&lds_y[(sr * 66 + colh) * 32 + s * 8]) = z;
  }

  // ---- stage: 640 units of (row sr, ic-slice s, col-quad c4)
#pragma unroll
  for (int it = 0; it < 3; ++it) {
    int unit = tid + it * 256;
    if (unit < 640) {
      int sr = unit >> 6;
      int rem = unit & 63;
      int s = rem >> 4, c4 = rem & 15;
      int ic0 = s * 8;
      int lr = h0 - 1 + sr;          // region-local input row
      short8 packs[4];
#pragma unroll
      for (int j = 0; j < 4; ++j) packs[j] = short8{0,0,0,0,0,0,0,0};
      if (lr >= 0 && lr < 64) {
        int grow = R * 64 + lr;
        const float* xp =
            x + (((size_t)(b * 32 + ic0) * 256 + grow) * 256) + Cc * 64 + c4 * 4;
#pragma unroll
        for (int k = 0; k < 8; ++k) {
          float4 v = *reinterpret_cast<const float4*>(xp + (size_t)k * 65536);
          float a = wsA[p * 32 + ic0 + k];
          float bb = wsB[p * 32 + ic0 + k];
          float e0 = fmaf(a, v.x, bb); e0 = e0 > 0.f ? e0 : pa * e0;
          float e1 = fmaf(a, v.y, bb); e1 = e1 > 0.f ? e1 : pa * e1;
          float e2 = fmaf(a, v.z, bb); e2 = e2 > 0.f ? e2 : pa * e2;
          float e3 = fmaf(a, v.w, bb); e3 = e3 > 0.f ? e3 : pa * e3;
          packs[0][k] = f2bf(e0);
          packs[1][k] = f2bf(e1);
          packs[2][k] = f2bf(e2);
          packs[3][k] = f2bf(e3);
        }
      }
#pragma unroll
      for (int j = 0; j < 4; ++j) {
        int col = 1 + c4 * 4 + j;
        *reinterpret_cast<short8*>(&lds_y[(sr * 66 + col) * 32 + ic0]) =
            packs[j];
      }
    }
  }
  __syncthreads();

  // ---- load pre-packed weight fragments (A: m=oc, k=ic), 18 x b128
  bf16x8 wf[18];
#pragma unroll
  for (int th = 0; th < 18; ++th) {
    short8 sv = *reinterpret_cast<const short8*>(wfrag + ((size_t)th * 64 + lane) * 8);
    wf[th] = __builtin_bit_cast(bf16x8, sv);
  }

  int l15 = lane & 15, l4 = lane >> 4;
  f32x4 bias0, bias1;
#pragma unroll
  for (int i = 0; i < 4; ++i) {
    bias0[i] = conv_b[l4 * 4 + i];
    bias1[i] = conv_b[16 + l4 * 4 + i];
  }

  int wv = tid >> 6;                 // wave id 0..3
  for (int g = 0; g < 8; ++g) {
    int gi = wv * 8 + g;             // 0..31: r = gi>>2, col-group = gi&3
    int r = gi >> 2;
    int c0 = (gi & 3) * 16;
    f32x4 acc0 = bias0, acc1 = bias1;
#pragma unroll
    for (int t = 0; t < 9; ++t) {
      int dy = t / 3, dx = t - dy * 3;
      int sr = r + dy;
      int col = c0 + l15 + dx;       // halo shift: input col + 1
      short8 sv =
          *reinterpret_cast<const short8*>(&lds_y[(sr * 66 + col) * 32 + l4 * 8]);
      bf16x8 bv = __builtin_bit_cast(bf16x8, sv);
      acc0 = __builtin_amdgcn_mfma_f32_16x16x32_bf16(wf[t * 2], bv, acc0, 0, 0, 0);
      acc1 = __builtin_amdgcn_mfma_f32_16x16x32_bf16(wf[t * 2 + 1], bv, acc1, 0, 0, 0);
    }
    // D: row(m=oc) = l4*4+i (+h*16), col(n=pixel) = l15
    int grow = R * 64 + h0 + r;
    int gcol = Cc * 64 + c0 + l15;
    float* ob = out + (size_t)b * 32 * 65536 + (size_t)grow * 256 + gcol;
#pragma unroll
    for (int i = 0; i < 4; ++i) {
      ob[(size_t)(l4 * 4 + i) * 65536] = acc0[i];
      ob[(size_t)(16 + l4 * 4 + i) * 65536] = acc1[i];
    }
  }
}

extern "C" void kernel_launch(void* const* d_in, const int* in_sizes, int n_in,
                              void* d_out, int out_size, void* d_ws,
                              size_t ws_size, hipStream_t stream) {
  const float* x = (const float*)d_in[0];
  const float* gamma = (const float*)d_in[1];
  const float* beta = (const float*)d_in[2];
  const float* prelu_a = (const float*)d_in[3];
  const float* conv_w = (const float*)d_in[4];
  const float* conv_b = (const float*)d_in[5];
  float* out = (float*)d_out;

  float* ws = (float*)d_ws;
  float* ws_sum = ws;                          // 16384
  float* ws_sq = ws + 16384;                   // 16384
  float* wsA = ws + 32768;                     // 512
  float* wsB = ws + 33280;                     // 512
  unsigned short* wfrag = (unsigned short*)(ws + 33792);  // 18*64*8 ushort

  weights_prep<<<5, 256, 0, stream>>>(conv_w, wfrag);
  stats_partial<<<16384, 256, 0, stream>>>(x, ws_sum, ws_sq);
  stats_finalize<<<1, 512, 0, stream>>>(ws_sum, ws_sq, gamma, beta, wsA, wsB);
  conv_mfma<<<4096, 256, 0, stream>>>(x, wfrag, conv_b, prelu_a, wsA, wsB, out);
}

// Round 3
// 200.888 us; speedup vs baseline: 6.4373x; 1.0264x over previous
//
#include <hip/hip_runtime.h>
#include <hip/hip_bf16.h>

// B=32, C=32, H=W=256, regions 4x4 of 64x64.
// Per (region p, channel c): mean/var over (B,64,64). Normalize+PReLU, then
// 3x3 conv per region (zero-padded at region borders) + bias.
// Conv via bf16 MFMA implicit-GEMM: m=oc, n=pixel, k=ic; 9 taps accumulate.

#define EPS 1e-5f

typedef float f32x4 __attribute__((ext_vector_type(4)));
typedef __bf16 bf16x8 __attribute__((ext_vector_type(8)));
typedef short short8 __attribute__((ext_vector_type(8)));

__device__ inline short f2bf(float f) {
  union { __hip_bfloat16 h; short s; } u;
  u.h = __float2bfloat16(f);
  return u.s;
}

// ---------------- Kernel 1: per-(b,c) plane stats, contiguous sweep ----------
// 1024 blocks, one (b,c) plane (256KB) each. Thread t: Cc=(t>>4)&3 fixed;
// iter chunk R = i>>4 compile-time. Fully coalesced 4KB/iteration.
// ws layout: [b][c][p] = (b*32+c)*16 + p.
__global__ __launch_bounds__(256) void stats_partial(
    const float* __restrict__ x, float* __restrict__ ws_sum,
    float* __restrict__ ws_sq) {
  int plane = blockIdx.x;            // b*32 + c
  const float* base = x + (size_t)plane * 65536;
  int t = threadIdx.x;
  float s[4] = {0.f, 0.f, 0.f, 0.f}, q[4] = {0.f, 0.f, 0.f, 0.f};
#pragma unroll
  for (int R = 0; R < 4; ++R) {
#pragma unroll
    for (int ii = 0; ii < 16; ++ii) {
      int idx4 = (R * 16 + ii) * 256 + t;     // float4 index; row=idx4>>6
      float4 v = *reinterpret_cast<const float4*>(base + (size_t)idx4 * 4);
      s[R] += (v.x + v.y) + (v.z + v.w);
      q[R] += (v.x * v.x + v.y * v.y) + (v.z * v.z + v.w * v.w);
    }
  }
  // reduce within 16-lane groups (lanes share Cc)
#pragma unroll
  for (int R = 0; R < 4; ++R) {
#pragma unroll
    for (int off = 8; off; off >>= 1) {
      s[R] += __shfl_down(s[R], off);
      q[R] += __shfl_down(q[R], off);
    }
  }
  __shared__ float red[2][4][4][4];  // [s|q][wave][Cc][R]
  int lane = t & 63, wv = t >> 6;
  if ((lane & 15) == 0) {
    int Cc = lane >> 4;
#pragma unroll
    for (int R = 0; R < 4; ++R) {
      red[0][wv][Cc][R] = s[R];
      red[1][wv][Cc][R] = q[R];
    }
  }
  __syncthreads();
  if (t < 16) {                      // t == p, R=p>>2, Cc=p&3
    int R = t >> 2, Cc = t & 3;
    float S = 0.f, Q = 0.f;
#pragma unroll
    for (int w = 0; w < 4; ++w) {
      S += red[0][w][Cc][R];
      Q += red[1][w][Cc][R];
    }
    ws_sum[plane * 16 + t] = S;
    ws_sq[plane * 16 + t] = Q;
  }
}

// ---------------- Kernel 2: finalize per-(p,c) scale/shift ----------------
__global__ __launch_bounds__(512) void stats_finalize(
    const float* __restrict__ ws_sum, const float* __restrict__ ws_sq,
    const float* __restrict__ gamma, const float* __restrict__ beta,
    float* __restrict__ wsA, float* __restrict__ wsB) {
  int j = threadIdx.x;               // 0..511
  int p = j >> 5, c = j & 31;
  float S = 0.f, Q = 0.f;
#pragma unroll
  for (int b = 0; b < 32; ++b) {
    int idx = (b * 32 + c) * 16 + p;
    S += ws_sum[idx];
    Q += ws_sq[idx];
  }
  const float inv = 1.0f / 131072.0f;
  float mean = S * inv;
  float var = Q * inv - mean * mean;
  float rstd = rsqrtf(var + EPS);
  float a = rstd * gamma[c];
  float bb = beta[c] - mean * a;
  wsA[p * 32 + c] = a;
  wsB[p * 32 + c] = bb;
}

// ---------------- Kernel 3: pack conv_w into MFMA A-fragments ----------------
// wfrag[(t*2+h)*64 + lane] = 8 bf16: A[m=oc][k=ic] for tap t, oc-half h.
// lane: oc = h*16 + (lane&15); ic = (lane>>4)*8 + j.
__global__ __launch_bounds__(256) void weights_prep(
    const float* __restrict__ conv_w, unsigned short* __restrict__ wfrag) {
  int idx = blockIdx.x * 256 + threadIdx.x;
  if (idx >= 18 * 64) return;
  int lane = idx & 63;
  int th = idx >> 6;                 // t*2 + h
  int t = th >> 1, h = th & 1;
  int dy = t / 3, dx = t - dy * 3;
  int oc = h * 16 + (lane & 15);
  int ic0 = (lane >> 4) * 8;
#pragma unroll
  for (int j = 0; j < 8; ++j) {
    float w = conv_w[((oc * 32 + ic0 + j) * 3 + dy) * 3 + dx];
    wfrag[(size_t)idx * 8 + j] = (unsigned short)f2bf(w);
  }
}

// ---------------- Kernel 4: normalize+prelu -> LDS bf16 -> MFMA conv ----------------
// block = (b, p, rt): 8 output rows x 64 cols of one region. 4 waves.
// LDS: [10 rows][66 cols][32 ic] bf16 (col 0 and 65 = zero halo).
// XCD-chunk-swizzled so consecutive rt tiles share an L2 (halo reuse).
__global__ __launch_bounds__(256) void conv_mfma(
    const float* __restrict__ x, const unsigned short* __restrict__ wfrag,
    const float* __restrict__ conv_b, const float* __restrict__ prelu_a,
    const float* __restrict__ wsA, const float* __restrict__ wsB,
    float* __restrict__ out) {
  __shared__ short lds_y[10 * 66 * 32];  // 42240 B

  int blk0 = blockIdx.x;             // 4096 blocks; chunked XCD swizzle
  int blk = (blk0 & 7) * 512 + (blk0 >> 3);
  int rt = blk & 7;
  int p = (blk >> 3) & 15;
  int b = blk >> 7;
  int R = p >> 2, Cc = p & 3;
  int h0 = rt * 8;
  int tid = threadIdx.x;
  int lane = tid & 63;
  float pa = prelu_a[0];

  // ---- per-thread-fixed staging decomposition
  int s = (tid >> 4) & 3;            // ic-slice, fixed per thread
  int c4 = tid & 15;                 // col-quad, fixed per thread
  int srb = tid >> 6;                // base staged-row
  int ic0 = s * 8;

  // preload norm coeffs for this thread's 8 channels (once per block)
  float4 a0 = *reinterpret_cast<const float4*>(wsA + p * 32 + ic0);
  float4 a1 = *reinterpret_cast<const float4*>(wsA + p * 32 + ic0 + 4);
  float4 bb0 = *reinterpret_cast<const float4*>(wsB + p * 32 + ic0);
  float4 bb1 = *reinterpret_cast<const float4*>(wsB + p * 32 + ic0 + 4);
  float a_r[8] = {a0.x, a0.y, a0.z, a0.w, a1.x, a1.y, a1.z, a1.w};
  float b_r[8] = {bb0.x, bb0.y, bb0.z, bb0.w, bb1.x, bb1.y, bb1.z, bb1.w};

  // weight fragments + bias: issue early, independent of LDS staging
  bf16x8 wf[18];
#pragma unroll
  for (int th = 0; th < 18; ++th) {
    short8 sv =
        *reinterpret_cast<const short8*>(wfrag + ((size_t)th * 64 + lane) * 8);
    wf[th] = __builtin_bit_cast(bf16x8, sv);
  }
  int l15 = lane & 15, l4 = lane >> 4;
  f32x4 bias0, bias1;
#pragma unroll
  for (int i = 0; i < 4; ++i) {
    bias0[i] = conv_b[l4 * 4 + i];
    bias1[i] = conv_b[16 + l4 * 4 + i];
  }

  // zero the left/right halo columns (10 rows x 2 cols x 4 ic-slices)
  if (tid < 80) {
    int sr = tid >> 3;
    int rem = tid & 7;
    int colh = (rem & 1) ? 65 : 0;
    int ss = rem >> 1;
    short8 z = {0, 0, 0, 0, 0, 0, 0, 0};
    *reinterpret_cast<short8*>(&lds_y[(sr * 66 + colh) * 32 + ss * 8]) = z;
  }

  // ---- stage 10 rows x 64 cols x 32 ic
#pragma unroll
  for (int it = 0; it < 3; ++it) {
    if (it < 2 || tid < 128) {
      int sr = srb + it * 4;         // staged row 0..9
      int lr = h0 - 1 + sr;          // region-local input row
      short8 packs[4];
#pragma unroll
      for (int j = 0; j < 4; ++j) packs[j] = short8{0, 0, 0, 0, 0, 0, 0, 0};
      if (lr >= 0 && lr < 64) {
        const float* xp =
            x + (((size_t)(b * 32 + ic0) * 256 + R * 64 + lr) * 256) +
            Cc * 64 + c4 * 4;
#pragma unroll
        for (int k = 0; k < 8; ++k) {
          float4 v = *reinterpret_cast<const float4*>(xp + (size_t)k * 65536);
          float e0 = fmaf(a_r[k], v.x, b_r[k]); e0 = e0 > 0.f ? e0 : pa * e0;
          float e1 = fmaf(a_r[k], v.y, b_r[k]); e1 = e1 > 0.f ? e1 : pa * e1;
          float e2 = fmaf(a_r[k], v.z, b_r[k]); e2 = e2 > 0.f ? e2 : pa * e2;
          float e3 = fmaf(a_r[k], v.w, b_r[k]); e3 = e3 > 0.f ? e3 : pa * e3;
          packs[0][k] = f2bf(e0);
          packs[1][k] = f2bf(e1);
          packs[2][k] = f2bf(e2);
          packs[3][k] = f2bf(e3);
        }
      }
#pragma unroll
      for (int j = 0; j < 4; ++j) {
        int col = 1 + c4 * 4 + j;
        *reinterpret_cast<short8*>(&lds_y[(sr * 66 + col) * 32 + ic0]) =
            packs[j];
      }
    }
  }
  __syncthreads();

  // ---- MFMA: each wave does 8 groups of (row r, 16-col block)
  int wv = tid >> 6;                 // wave id 0..3
  for (int g = 0; g < 8; ++g) {
    int gi = wv * 8 + g;             // r = gi>>2, col-group = gi&3
    int r = gi >> 2;
    int c0 = (gi & 3) * 16;
    f32x4 acc0 = bias0, acc1 = bias1;
#pragma unroll
    for (int t = 0; t < 9; ++t) {
      int dy = t / 3, dx = t - dy * 3;
      int sr = r + dy;
      int col = c0 + l15 + dx;       // halo shift: input col + 1
      short8 sv = *reinterpret_cast<const short8*>(
          &lds_y[(sr * 66 + col) * 32 + l4 * 8]);
      bf16x8 bv = __builtin_bit_cast(bf16x8, sv);
      acc0 = __builtin_amdgcn_mfma_f32_16x16x32_bf16(wf[t * 2], bv, acc0, 0, 0, 0);
      acc1 = __builtin_amdgcn_mfma_f32_16x16x32_bf16(wf[t * 2 + 1], bv, acc1, 0, 0, 0);
    }
    // D: row(m=oc) = l4*4+i (+h*16), col(n=pixel) = l15
    int grow = R * 64 + h0 + r;
    int gcol = Cc * 64 + c0 + l15;
    float* ob =
        out + (size_t)b * 32 * 65536 + (size_t)grow * 256 + gcol;
#pragma unroll
    for (int i = 0; i < 4; ++i) {
      ob[(size_t)(l4 * 4 + i) * 65536] = acc0[i];
      ob[(size_t)(16 + l4 * 4 + i) * 65536] = acc1[i];
    }
  }
}

extern "C" void kernel_launch(void* const* d_in, const int* in_sizes, int n_in,
                              void* d_out, int out_size, void* d_ws,
                              size_t ws_size, hipStream_t stream) {
  const float* x = (const float*)d_in[0];
  const float* gamma = (const float*)d_in[1];
  const float* beta = (const float*)d_in[2];
  const float* prelu_a = (const float*)d_in[3];
  const float* conv_w = (const float*)d_in[4];
  const float* conv_b = (const float*)d_in[5];
  float* out = (float*)d_out;

  float* ws = (float*)d_ws;
  float* ws_sum = ws;                          // 16384
  float* ws_sq = ws + 16384;                   // 16384
  float* wsA = ws + 32768;                     // 512
  float* wsB = ws + 33280;                     // 512
  unsigned short* wfrag = (unsigned short*)(ws + 33792);  // 18*64*8 ushort

  weights_prep<<<5, 256, 0, stream>>>(conv_w, wfrag);
  stats_partial<<<1024, 256, 0, stream>>>(x, ws_sum, ws_sq);
  stats_finalize<<<1, 512, 0, stream>>>(ws_sum, ws_sq, gamma, beta, wsA, wsB);
  conv_mfma<<<4096, 256, 0, stream>>>(x, wfrag, conv_b, prelu_a, wsA, wsB, out);
}